// Round 13
// baseline (177.619 us; speedup 1.0000x reference)
//
#include <hip/hip_runtime.h>
#include <hip/hip_bf16.h>

// PCGraphConv: iterative predictive-coding message passing.
// N_V=2000, N_SENS=784, N_E=500000, BATCH=32, T=5, lr=0.1.
// R12: fixed-capacity bucket sort (no scan chain, no transpose).
//  - k_place_init (250 blocks): each block scatters its 2000 edges into
//    block-private 64-slot buckets for BOTH directions (dst-tile for WA,
//    interior src-tile for WB) via LDS cursors; writes counts; also does the
//    full init (v_cur, fxA, sensory out rows, frag-pad zero).
//    Capacity 64 vs Binomial(2000,1/125) mean 16, sigma 4 => >10 sigma.
//  - k_build (402 blocks): A-role (250) accumulates dst-buckets into LDS
//    fp32 acc[8][2016], emits WAbf fragments; B-role (152) accumulates
//    src-buckets, emits WBf directly (WAd + strided trB deleted).
//  - 5 x (k_gemm1 250 blocks, k_gemm2 152 blocks): operand-swapped MFMA
//    16x16x32_bf16, K fully unrolled, fused epilogues; final gemm2 writes
//    interior out rows. 12 dispatches total.
// Fallback: proven R4 CSR path if ws too small.

#define N_V     2000
#define N_SENS  784
#define N_INT   (N_V - N_SENS)   // 1216
#define N_E     500000
#define T_STEPS 5
#define LR_VAL  0.1f
#define NVB     (N_V * 32)       // 64000
#define NVH     (N_V * 16)       // 32000
#define KP      2016             // padded K (63 chunks of 32)
#define NCH     63               // K chunks
#define NT1     125              // dst tiles (125*16 = 2000)
#define NT2     76               // interior src tiles (76*16 = 1216)
#define FRAG_N  (2 * NCH * 64 * 8)   // 64512 u16 per A-frag table
#define NBLK    250              // place blocks
#define EPB     2000             // edges per place block
#define CAP     64               // bucket capacity per (tile, block)

typedef float  f32x4 __attribute__((ext_vector_type(4)));
typedef short  s16x8 __attribute__((ext_vector_type(8)));

__device__ __forceinline__ float bits_to_f32(unsigned u) {
    union { unsigned u; float f; } c; c.u = u; return c.f;
}
__device__ __forceinline__ unsigned f32_to_bits(float f) {
    union { float f; unsigned u; } c; c.f = f; return c.u;
}
__device__ __forceinline__ unsigned short f32_to_bf16(float f) {
    unsigned u = f32_to_bits(f);
    return (unsigned short)((u + 0x7FFFu + ((u >> 16) & 1u)) >> 16);  // RNE
}
__device__ __forceinline__ float bf16_to_f32(unsigned short s) {
    return bits_to_f32((unsigned)s << 16);
}

// A-fragment u16 index for element (k, b) of fx/err tables (m = b&15).
__device__ __forceinline__ int aposKB(int k, int b) {
    int c = k >> 5, q = (k >> 3) & 3, j = k & 7;
    int h = b >> 4, m = b & 15;
    return (((h * NCH + c) * 64) + q * 16 + m) * 8 + j;
}

// ------------------------- dense/MFMA path -------------------------------

// 250 blocks: bucket-scatter both directions + counts + full init.
__global__ __launch_bounds__(256) void k_place_init(
        const int* __restrict__ src, const int* __restrict__ dst,
        const float* __restrict__ w, const float* __restrict__ vin,
        unsigned* __restrict__ pkA, unsigned* __restrict__ pkB,
        int* __restrict__ cntA, int* __restrict__ cntB,
        float* __restrict__ v_cur, unsigned short* __restrict__ fxA,
        unsigned short* __restrict__ errA, float* __restrict__ out) {
    __shared__ int curA[NT1];
    __shared__ int curB[NT2];
    int bx = blockIdx.x, tid = threadIdx.x;
    for (int t = tid; t < NT1; t += 256) curA[t] = 0;
    for (int t = tid; t < NT2; t += 256) curB[t] = 0;
    __syncthreads();
    int base = bx * EPB;
    for (int e = base + tid; e < base + EPB; e += 256) {
        int s = src[e], d = dst[e];
        unsigned wb = (unsigned)f32_to_bf16(w[e]);
        {   // A: by dst-tile, column = src
            int t = d >> 4;
            int idx = atomicAdd(&curA[t], 1);
            if (idx < CAP)
                pkA[(size_t)t * (NBLK * CAP) + bx * CAP + idx] =
                    (wb << 16) | ((unsigned)(d & 15) << 11) | (unsigned)s;
        }
        if (s >= N_SENS) {   // B: by interior src-tile, column = dst
            int t = (s - N_SENS) >> 4;
            int idx = atomicAdd(&curB[t], 1);
            if (idx < CAP)
                pkB[(size_t)t * (NBLK * CAP) + bx * CAP + idx] =
                    (wb << 16) | ((unsigned)((s - N_SENS) & 15) << 11) | (unsigned)d;
        }
    }
    __syncthreads();
    for (int t = tid; t < NT1; t += 256)
        cntA[t * NBLK + bx] = (curA[t] < CAP) ? curA[t] : CAP;
    for (int t = tid; t < NT2; t += 256)
        cntB[t * NBLK + bx] = (curB[t] < CAP) ? curB[t] : CAP;

    // init: exactly one element per thread (250*256 == NVB)
    {
        int t = bx * 256 + tid;
        float x = vin[t];
        int b = t / N_V;
        int i = t - b * N_V;
        v_cur[(i << 5) + b] = x;
        fxA[aposKB(i, b)] = f32_to_bf16(tanhf(x));
        if (i < N_SENS) out[t] = x;
        if (t < 16 * 32) {   // zero frag pads k in [2000,2016)
            int k = 2000 + (t >> 5), bb = t & 31;
            fxA[aposKB(k, bb)] = 0;
            errA[aposKB(k, bb)] = 0;
        }
    }
}

// 402 blocks: bx<250 A-role (tile=bx>>1, half=bx&1) -> WAbf;
// bx>=250 B-role (sub=bx-250) -> WBf.
__global__ __launch_bounds__(256) void k_build(
        const unsigned* __restrict__ pkA, const unsigned* __restrict__ pkB,
        const int* __restrict__ cntA, const int* __restrict__ cntB,
        uint4* __restrict__ WAbf4, uint4* __restrict__ WBf4) {
    __shared__ float acc[8][KP];   // 64512 B
    __shared__ int scnt[NBLK];     // 1000 B  (total 65512 <= 64KB+... fits 160KB CU)
    int bx = blockIdx.x, tid = threadIdx.x;
    int isA = (bx < 250);
    int sub = isA ? bx : bx - 250;
    int tile = sub >> 1, half = sub & 1;
    const unsigned* pk = isA ? (pkA + (size_t)tile * (NBLK * CAP))
                             : (pkB + (size_t)tile * (NBLK * CAP));
    const int* cnt = isA ? (cntA + tile * NBLK) : (cntB + tile * NBLK);

    for (int i = tid; i < 8 * KP / 4; i += 256)
        ((float4*)&acc[0][0])[i] = make_float4(0.f, 0.f, 0.f, 0.f);
    for (int i = tid; i < NBLK; i += 256) scnt[i] = cnt[i];
    __syncthreads();

    for (int i = tid; i < NBLK * CAP; i += 256) {
        int b = i >> 6, s = i & (CAP - 1);
        if (s < scnt[b]) {
            unsigned p = pk[i];
            int row = (int)((p >> 11) & 15u);
            if ((row >> 3) == half)
                atomicAdd(&acc[row & 7][p & 0x7FFu],
                          bf16_to_f32((unsigned short)(p >> 16)));
        }
    }
    __syncthreads();

    uint4* o4 = isA ? WAbf4 : WBf4;
    for (int i = tid; i < 8 * 252; i += 256) {
        int rr = i / 252, g = i - rr * 252;
        int c = g >> 2, q = g & 3;
        int col = g * 8;
        unsigned short r[8];
        #pragma unroll
        for (int j = 0; j < 8; ++j) r[j] = f32_to_bf16(acc[rr][col + j]);
        o4[((tile * NCH + c) * 64) + q * 16 + half * 8 + rr] = *(const uint4*)r;
    }
}

// GEMM1: err = v - fx.WA^T ; 250 blocks = 125 tiles x 2 batch-halves.
__global__ __launch_bounds__(256) void k_gemm1(
        const uint4* __restrict__ WAbf4, const uint4* __restrict__ fxA4,
        const float* __restrict__ v_cur, unsigned short* __restrict__ errA) {
    __shared__ float red[1300];
    int bx = blockIdx.x, tid = threadIdx.x;
    int w = tid >> 6, l = tid & 63;
    int tile = bx >> 1, h = bx & 1;
    int cbeg = w * 16;
    const uint4* bp = WAbf4 + (size_t)tile * NCH * 64 + cbeg * 64 + l;
    const uint4* ap = fxA4 + (size_t)h * NCH * 64 + cbeg * 64 + l;
    f32x4 acc = {0.f, 0.f, 0.f, 0.f};
    #pragma unroll
    for (int cc = 0; cc < 16; ++cc) {
        if (cbeg + cc < NCH) {
            uint4 bfrag = bp[cc * 64];
            uint4 a = ap[cc * 64];
            acc = __builtin_amdgcn_mfma_f32_16x16x32_bf16(
                      *(s16x8*)&a, *(s16x8*)&bfrag, acc, 0, 0, 0);
        }
    }
    float* my = &red[w * 325 + l * 5];
    #pragma unroll
    for (int r = 0; r < 4; ++r) my[r] = acc[r];
    __syncthreads();
    if (w == 0) {
        float s[4];
        #pragma unroll
        for (int r = 0; r < 4; ++r)
            s[r] = red[l * 5 + r] + red[325 + l * 5 + r]
                 + red[650 + l * 5 + r] + red[975 + l * 5 + r];
        int i = tile * 16 + (l & 15);
        int q = l >> 4;
        int c2 = i >> 5, q2 = (i >> 3) & 3, j2 = i & 7;
        const float4 v4 = *(const float4*)(v_cur + (i << 5) + h * 16 + q * 4);
        int base = ((h * NCH + c2) * 64 + q2 * 16) * 8 + j2;
        errA[base + (q * 4 + 0) * 8] = f32_to_bf16(v4.x - s[0]);
        errA[base + (q * 4 + 1) * 8] = f32_to_bf16(v4.y - s[1]);
        errA[base + (q * 4 + 2) * 8] = f32_to_bf16(v4.z - s[2]);
        errA[base + (q * 4 + 3) * 8] = f32_to_bf16(v4.w - s[3]);
    }
}

// GEMM2: back = err.WB^T ; 152 blocks; fused v update + tanh + fx repack;
// final: also store interior out rows.
__global__ __launch_bounds__(256) void k_gemm2(
        const uint4* __restrict__ WBf4, const uint4* __restrict__ errA4,
        unsigned short* __restrict__ errA, unsigned short* __restrict__ fxA,
        float* __restrict__ v_cur, float* __restrict__ out, int final_step) {
    __shared__ float red[1300];
    int bx = blockIdx.x, tid = threadIdx.x;
    int w = tid >> 6, l = tid & 63;
    int tile = bx >> 1, h = bx & 1;
    int cbeg = w * 16;
    const uint4* bp = WBf4 + (size_t)tile * NCH * 64 + cbeg * 64 + l;
    const uint4* ap = errA4 + (size_t)h * NCH * 64 + cbeg * 64 + l;
    f32x4 acc = {0.f, 0.f, 0.f, 0.f};
    #pragma unroll
    for (int cc = 0; cc < 16; ++cc) {
        if (cbeg + cc < NCH) {
            uint4 bfrag = bp[cc * 64];
            uint4 a = ap[cc * 64];
            acc = __builtin_amdgcn_mfma_f32_16x16x32_bf16(
                      *(s16x8*)&a, *(s16x8*)&bfrag, acc, 0, 0, 0);
        }
    }
    float* my = &red[w * 325 + l * 5];
    #pragma unroll
    for (int r = 0; r < 4; ++r) my[r] = acc[r];
    __syncthreads();
    if (w == 0) {
        float s[4];
        #pragma unroll
        for (int r = 0; r < 4; ++r)
            s[r] = red[l * 5 + r] + red[325 + l * 5 + r]
                 + red[650 + l * 5 + r] + red[975 + l * 5 + r];
        int j = N_SENS + tile * 16 + (l & 15);
        int q = l >> 4;
        int c2 = j >> 5, q2 = (j >> 3) & 3, j2 = j & 7;
        float4 v4 = *(const float4*)(v_cur + (j << 5) + h * 16 + q * 4);
        int base = ((h * NCH + c2) * 64 + q2 * 16) * 8 + j2;
        float vv[4] = {v4.x, v4.y, v4.z, v4.w};
        #pragma unroll
        for (int r = 0; r < 4; ++r) {
            float e0 = bf16_to_f32(errA[base + (q * 4 + r) * 8]);
            float fxv = tanhf(vv[r]);
            float vn = vv[r] - LR_VAL * (e0 - (1.f - fxv * fxv) * s[r]);
            vv[r] = vn;
            fxA[base + (q * 4 + r) * 8] = f32_to_bf16(tanhf(vn));
        }
        float4 o = {vv[0], vv[1], vv[2], vv[3]};
        *(float4*)(v_cur + (j << 5) + h * 16 + q * 4) = o;
        if (final_step) {
            #pragma unroll
            for (int r = 0; r < 4; ++r) {
                int b = h * 16 + q * 4 + r;
                out[b * N_V + j] = vv[r];
            }
        }
    }
}

// ------------------------- fallback path (R4 CSR, proven) ----------------

__global__ void k_zero_i32(int* a, int n) {
    int t = blockIdx.x * blockDim.x + threadIdx.x;
    if (t < n) a[t] = 0;
}

__global__ void k_hist(const int* __restrict__ src, const int* __restrict__ dst,
                       int* cnt_dst, int* cnt_src) {
    int e = blockIdx.x * blockDim.x + threadIdx.x;
    if (e < N_E) {
        atomicAdd(&cnt_dst[dst[e]], 1);
        atomicAdd(&cnt_src[src[e]], 1);
    }
}

__global__ __launch_bounds__(1024) void k_scan(int* cnt_a, int* rp_a,
                                               int* cnt_b, int* rp_b) {
    __shared__ int sh[1024];
    int t = threadIdx.x;
    for (int pass = 0; pass < 2; ++pass) {
        int* cnt = pass ? cnt_b : cnt_a;
        int* rp  = pass ? rp_b  : rp_a;
        int i0 = 2 * t, i1 = 2 * t + 1;
        int c0 = (i0 < N_V) ? cnt[i0] : 0;
        int c1 = (i1 < N_V) ? cnt[i1] : 0;
        __syncthreads();
        sh[t] = c0 + c1;
        __syncthreads();
        for (int off = 1; off < 1024; off <<= 1) {
            int v = (t >= off) ? sh[t - off] : 0;
            __syncthreads();
            sh[t] += v;
            __syncthreads();
        }
        int incl = sh[t];
        int e0 = incl - (c0 + c1);
        int e1 = e0 + c0;
        if (i0 <= N_V) rp[i0] = e0;
        if (i1 <= N_V) rp[i1] = e1;
        if (i0 < N_V) cnt[i0] = e0;
        if (i1 < N_V) cnt[i1] = e1;
    }
}

__global__ void k_scatter(const int* __restrict__ src, const int* __restrict__ dst,
                          const float* __restrict__ w,
                          int* cur_dst, int* cur_src,
                          unsigned* __restrict__ pk_dst, unsigned* __restrict__ pk_src) {
    int e = blockIdx.x * blockDim.x + threadIdx.x;
    if (e < N_E) {
        int s = src[e], d = dst[e];
        unsigned wbits = (unsigned)f32_to_bf16(w[e]);
        int p = atomicAdd(&cur_dst[d], 1);
        pk_dst[p] = (wbits << 16) | (unsigned)s;
        int q = atomicAdd(&cur_src[s], 1);
        pk_src[q] = (wbits << 16) | (unsigned)d;
    }
}

__global__ void k_cast_in(const float* __restrict__ vin, float* __restrict__ v) {
    int t = blockIdx.x * blockDim.x + threadIdx.x;
    if (t < NVB) {
        int i = t >> 5, b = t & 31;
        v[t] = vin[b * N_V + i];
    }
}

__global__ void k_fx_csr(const float* __restrict__ v, unsigned short* __restrict__ fx) {
    int t = blockIdx.x * blockDim.x + threadIdx.x;
    if (t < NVB) {
        int i = t >> 5, b = t & 31;
        int h = b >> 4, b16 = b & 15;
        fx[h * NVH + i * 16 + b16] = f32_to_bf16(tanhf(v[t]));
    }
}

__global__ __launch_bounds__(256) void k_pred_err(
        const float* __restrict__ v, const unsigned short* __restrict__ fx,
        const int* __restrict__ rp, const unsigned* __restrict__ pk,
        unsigned short* __restrict__ err) {
    __shared__ unsigned short tab[NVH];
    int h  = blockIdx.x / 250;
    int vg = blockIdx.x % 250;
    {
        const uint4* g = (const uint4*)(fx + h * NVH);
        uint4* l = (uint4*)tab;
        for (int i = threadIdx.x; i < NVH / 8; i += 256) l[i] = g[i];
    }
    __syncthreads();
    int wave = threadIdx.x >> 6;
    int lane = threadIdx.x & 63;
    int b16 = lane & 15, epar = lane >> 4;
    for (int k = 0; k < 2; ++k) {
        int vid = vg * 8 + wave * 2 + k;
        int beg = rp[vid], end = rp[vid + 1];
        float sum = 0.f;
        for (int e = beg + epar; e < end; e += 4) {
            unsigned p = pk[e];
            float w = bits_to_f32(p & 0xFFFF0000u);
            int nb = (int)(p & 0xFFFFu);
            sum += w * bf16_to_f32(tab[nb * 16 + b16]);
        }
        sum += __shfl_xor(sum, 16, 64);
        sum += __shfl_xor(sum, 32, 64);
        if (epar == 0) {
            float vo = v[(vid << 5) + h * 16 + b16];
            err[h * NVH + vid * 16 + b16] = f32_to_bf16(vo - sum);
        }
    }
}

__global__ __launch_bounds__(256) void k_back_upd(
        const unsigned short* __restrict__ fx, const unsigned short* __restrict__ err,
        const int* __restrict__ rp, const unsigned* __restrict__ pk,
        float* __restrict__ v) {
    __shared__ unsigned short tab[NVH];
    int h  = blockIdx.x / 152;
    int vg = blockIdx.x % 152;
    {
        const uint4* g = (const uint4*)(err + h * NVH);
        uint4* l = (uint4*)tab;
        for (int i = threadIdx.x; i < NVH / 8; i += 256) l[i] = g[i];
    }
    __syncthreads();
    int wave = threadIdx.x >> 6;
    int lane = threadIdx.x & 63;
    int b16 = lane & 15, epar = lane >> 4;
    for (int k = 0; k < 2; ++k) {
        int vid = N_SENS + vg * 8 + wave * 2 + k;
        if (vid >= N_V) continue;
        int beg = rp[vid], end = rp[vid + 1];
        float sum = 0.f;
        for (int e = beg + epar; e < end; e += 4) {
            unsigned p = pk[e];
            float w = bits_to_f32(p & 0xFFFF0000u);
            int nb = (int)(p & 0xFFFFu);
            sum += w * bf16_to_f32(tab[nb * 16 + b16]);
        }
        sum += __shfl_xor(sum, 16, 64);
        sum += __shfl_xor(sum, 32, 64);
        if (epar == 0) {
            float e0  = bf16_to_f32(tab[vid * 16 + b16]);
            float fxv = bf16_to_f32(fx[h * NVH + vid * 16 + b16]);
            float dv = e0 - (1.f - fxv * fxv) * sum;
            v[(vid << 5) + h * 16 + b16] -= LR_VAL * dv;
        }
    }
}

__global__ void k_out_fb(const float* __restrict__ v, float* __restrict__ out) {
    int t = blockIdx.x * blockDim.x + threadIdx.x;
    if (t < NVB) {
        int b = t / N_V;
        int i = t - b * N_V;
        out[t] = v[(i << 5) + b];
    }
}

// ------------------------- host -----------------------------------------

extern "C" void kernel_launch(void* const* d_in, const int* in_sizes, int n_in,
                              void* d_out, int out_size, void* d_ws, size_t ws_size,
                              hipStream_t stream) {
    const float* vals = (const float*)d_in[0];
    const float* wts  = (const float*)d_in[1];
    const int* ei = (const int*)d_in[2];
    const int* src = ei;
    const int* dst = ei + N_E;
    float* out = (float*)d_out;

    const int EB = (N_E + 255) / 256;

    // ws layout: pkA | pkB | cntA | cntB | WAbf | WBf | fxA | errA | v_cur
    const size_t PKA_N  = (size_t)NT1 * NBLK * CAP;   // 2,000,000 u32
    const size_t PKB_N  = (size_t)NT2 * NBLK * CAP;   // 1,216,000 u32
    const size_t WABF_T = (size_t)NT1 * NCH * 64;     // uint4 count
    const size_t WBF_T  = (size_t)NT2 * NCH * 64;
    const size_t need = PKA_N * 4 + PKB_N * 4 + (size_t)(NT1 + NT2) * NBLK * 4
                      + WABF_T * 16 + WBF_T * 16 + 2 * (size_t)FRAG_N * 2
                      + NVB * 4 + 1024;

    if (ws_size >= need) {
        unsigned* pkA = (unsigned*)d_ws;
        unsigned* pkB = pkA + PKA_N;
        int* cntA = (int*)(pkB + PKB_N);
        int* cntB = cntA + NT1 * NBLK;
        uint4* WAbf4 = (uint4*)(cntB + NT2 * NBLK);
        uint4* WBf4  = WAbf4 + WABF_T;
        unsigned short* fxA  = (unsigned short*)(WBf4 + WBF_T);
        unsigned short* errA = fxA + FRAG_N;
        float* v_cur = (float*)(errA + FRAG_N);

        k_place_init<<<NBLK, 256, 0, stream>>>(src, dst, wts, vals,
                                               pkA, pkB, cntA, cntB,
                                               v_cur, fxA, errA, out);
        k_build<<<402, 256, 0, stream>>>(pkA, pkB, cntA, cntB, WAbf4, WBf4);

        for (int t = 0; t < T_STEPS; ++t) {
            k_gemm1<<<250, 256, 0, stream>>>(WAbf4, (const uint4*)fxA, v_cur, errA);
            k_gemm2<<<152, 256, 0, stream>>>(WBf4, (const uint4*)errA, errA, fxA,
                                             v_cur, out, (t == T_STEPS - 1) ? 1 : 0);
        }
    } else {
        float* v_cur = (float*)d_ws;
        unsigned short* fx_g  = (unsigned short*)(v_cur + NVB);
        unsigned short* err_g = fx_g + NVB;
        int* rp_dst  = (int*)(err_g + NVB);
        int* rp_src  = rp_dst + 2048;
        int* cur_dst = rp_src + 2048;
        int* cur_src = cur_dst + 2048;
        unsigned* pk_dst = (unsigned*)(cur_src + 2048);
        unsigned* pk_src = pk_dst + N_E;

        k_zero_i32<<<16, 256, 0, stream>>>(cur_dst, 4096);
        k_hist<<<EB, 256, 0, stream>>>(src, dst, cur_dst, cur_src);
        k_scan<<<1, 1024, 0, stream>>>(cur_dst, rp_dst, cur_src, rp_src);
        k_scatter<<<EB, 256, 0, stream>>>(src, dst, wts, cur_dst, cur_src,
                                          pk_dst, pk_src);
        k_cast_in<<<250, 256, 0, stream>>>(vals, v_cur);
        for (int t = 0; t < T_STEPS; ++t) {
            k_fx_csr<<<250, 256, 0, stream>>>(v_cur, fx_g);
            k_pred_err<<<500, 256, 0, stream>>>(v_cur, fx_g, rp_dst, pk_dst, err_g);
            k_back_upd<<<304, 256, 0, stream>>>(fx_g, err_g, rp_src, pk_src, v_cur);
        }
        k_out_fb<<<250, 256, 0, stream>>>(v_cur, out);
    }
}